// Round 7
// baseline (609.135 us; speedup 1.0000x reference)
//
#include <hip/hip_runtime.h>
#include <hip/hip_cooperative_groups.h>
#include <stdint.h>

namespace cg = cooperative_groups;

// Problem: LTCCell  B=256, I=512, H=512. ALL tensors float32, output float32.
// R5: 2048 blocks, TB=8, accum 45us. R6 rcp-share FAILED. R7 manual
//   prefetch NEUTRAL. R8 store-partials NEUTRAL (but validated the raceless
//   float2-partial path; ws_size confirmed 256MiB). R9 TB=16 REGRESSED.
// R10 WIN: full unroll of ii loop -> accum 43.6us, VALUBusy 72%, VGPR 24,
//   total 119.2. Accum now ~issue-limited (busy 31.4us vs ~28.6 floor).
// R11 THEORY: budget 119.2 = 48.6 poison (fixed) + 43.6 accum + ~27
//   {memset+epi+launch boundaries}; boundary fit ~6-8us each across
//   R5/R8/R10. Fuse to ONE cooperative kernel: R10 accum body + float2
//   partial stores (no memset) + grid.sync() + epilogue on blocks 0..511.
//   2048 blocks == exact co-residency (8/CU, VGPR<=64 via launch_bounds).
//   Predict: fused dispatch 48-52us, total 100-110us. If >=117: boundary
//   model wrong -> roofline ~119. Fallbacks: coop-fail -> 2-launch ps ->
//   3-launch atomics.
constexpr int NB = 256;
constexpr int NI = 512;
constexpr int NH = 512;

constexpr int TB    = 8;    // batches register-blocked per lane
constexpr int NT    = 32;   // batch tiles: 256/8
constexpr int CHUNK = 32;   // reduction rows per block
constexpr int NSPL  = 32;   // splits: 16 sensory chunks + 16 inter chunks
constexpr int HBLK  = 256;  // h columns per block (== blockDim.x)
constexpr int GRID  = NSPL * NT * 2;  // 2048 blocks = 8/CU x 256 CU

__device__ __forceinline__ float fast_exp2(float x) {
#if __has_builtin(__builtin_amdgcn_exp2f)
    return __builtin_amdgcn_exp2f(x);
#else
    return exp2f(x);
#endif
}
__device__ __forceinline__ float fast_rcp(float x) {
#if __has_builtin(__builtin_amdgcn_rcpf)
    return __builtin_amdgcn_rcpf(x);
#else
    return 1.0f / x;
#endif
}

// R10 accum body (full unroll; measured 43.6us standalone). Lane <-> h
// column, 8 batches register-blocked per lane (r[8] ILP).
template <typename FlushFn>
__device__ __forceinline__ void ltc_accum_body(
    const float* __restrict__ inputs, const float* __restrict__ state,
    const float* __restrict__ smu, const float* __restrict__ ssg,
    const float* __restrict__ sW,  const float* __restrict__ ser,
    const float* __restrict__ imu, const float* __restrict__ isg,
    const float* __restrict__ iW,  const float* __restrict__ ier,
    FlushFn flush)
{
    __shared__ float xs[CHUNK][TB];   // x/state chunk, [row][batch]

    const int bi    = blockIdx.x;
    const int sigma = bi & (NSPL - 1);          // 32 splits
    const int btile = (bi >> 5) & (NT - 1);     // 32 batch tiles
    const int hhalf = bi >> 10;                 // 2 h halves
    const int b0 = btile * TB;
    const int h  = hhalf * HBLK + threadIdx.x;

    const bool sens = sigma < 16;
    const int  r0   = (sens ? sigma : sigma - 16) * CHUNK;

    // Side-selected pointers (block-uniform -> scalar select, no divergence).
    const float* __restrict__ src  = sens ? inputs : state;   // NB x 512
    const float* __restrict__ Pmu  = sens ? smu : imu;
    const float* __restrict__ Psg  = sens ? ssg : isg;
    const float* __restrict__ PW   = sens ? sW  : iW;
    const float* __restrict__ Per  = sens ? ser : ier;

    // Stage x/state chunk to LDS, [row][batch] layout. CHUNK*TB == 256.
    {
        const int ii = threadIdx.x >> 3, bb = threadIdx.x & (TB - 1);
        xs[ii][bb] = src[(b0 + bb) * 512 + r0 + ii];
    }
    __syncthreads();

    float num[TB], den[TB];
#pragma unroll
    for (int bb = 0; bb < TB; ++bb) { num[bb] = 0.f; den[bb] = 0.f; }

    const float LOG2E = 1.44269504088896340736f;

    // sigmoid((x-mu)*sig) = 1/(1+exp2(c - x*a)), a = sig*log2e, c = mu*a.
    // exp2 overflow -> inf -> rcp gives 0: correct saturation.
    // FULL unroll: compiler sees all 128 param loads -> deep load batching.
#pragma unroll
    for (int ii = 0; ii < CHUNK; ++ii) {
        const int p = (r0 + ii) * NH + h;          // coalesced across lanes
        const float mu = Pmu[p];
        const float a  = Psg[p] * LOG2E;
        const float W  = PW[p];
        const float We = W * Per[p];
        const float c  = mu * a;
        float r[TB];                               // 8 independent chains
#pragma unroll
        for (int bb = 0; bb < TB; ++bb)
            r[bb] = fast_rcp(1.0f + fast_exp2(c - xs[ii][bb] * a));
#pragma unroll
        for (int bb = 0; bb < TB; ++bb) {
            den[bb] += W  * r[bb];
            num[bb] += We * r[bb];
        }
    }

    flush(sigma, b0, h, num, den);
}

__device__ __forceinline__ void ltc_epilogue_math(
    int t, float wnum, float wden,
    const float* __restrict__ state,
    const float* __restrict__ vleak, const float* __restrict__ gleak,
    const float* __restrict__ cm, float* __restrict__ out)
{
    const int h = t & (NH - 1);
    const float st = state[t];
    const float gl = gleak[h];
    const float vl = vleak[h];
    const float c  = cm[h];
    const float eps = 1e-8f;
    const float G = gl + wden;
    const float tau = c / (G + eps);
    const float numerator = c * st + gl * vl + wnum;
    const float denominator = c + G;
    const float v_inf = numerator / (denominator + eps);
    const float next = v_inf + (st - v_inf) * expf(-0.1f / (tau + eps));
    out[t] = tanhf(next);
}

// ---------------- Path 0: single cooperative fused kernel -----------------
// ws layout: float2 wp[NSPL][NB][NH] partials (32 MiB; ws is 256 MiB).
__global__ __launch_bounds__(256, 8) void ltc_fused(
    const float* __restrict__ inputs, const float* __restrict__ state,
    const float* __restrict__ smu, const float* __restrict__ ssg,
    const float* __restrict__ sW,  const float* __restrict__ ser,
    const float* __restrict__ imu, const float* __restrict__ isg,
    const float* __restrict__ iW,  const float* __restrict__ ier,
    const float* __restrict__ vleak, const float* __restrict__ gleak,
    const float* __restrict__ cm,
    float2* __restrict__ wp, float* __restrict__ out)
{
    ltc_accum_body(inputs, state, smu, ssg, sW, ser, imu, isg, iW, ier,
        [&](int sigma, int b0, int h, const float* num, const float* den) {
#pragma unroll
            for (int bb = 0; bb < TB; ++bb)
                wp[((size_t)sigma * NB + (b0 + bb)) * NH + h] =
                    make_float2(num[bb], den[bb]);
        });

    cg::this_grid().sync();   // fences + barriers all 2048 co-resident blocks

    // Epilogue: blocks 0..511, one (b,h) per thread, coalesced.
    if (blockIdx.x < (NB * NH / 256)) {
        const int t = blockIdx.x * 256 + threadIdx.x;
        float wnum = 0.f, wden = 0.f;
#pragma unroll
        for (int s = 0; s < NSPL; ++s) {
            const float2 v = wp[(size_t)s * NB * NH + t];  // dwordx2
            wnum += v.x; wden += v.y;
        }
        ltc_epilogue_math(t, wnum, wden, state, vleak, gleak, cm, out);
    }
}

// ---------------- Path A: 2-launch partial-store fallback -----------------
__global__ __launch_bounds__(256, 8) void ltc_accum_ps(
    const float* __restrict__ inputs, const float* __restrict__ state,
    const float* __restrict__ smu, const float* __restrict__ ssg,
    const float* __restrict__ sW,  const float* __restrict__ ser,
    const float* __restrict__ imu, const float* __restrict__ isg,
    const float* __restrict__ iW,  const float* __restrict__ ier,
    float2* __restrict__ wp)
{
    ltc_accum_body(inputs, state, smu, ssg, sW, ser, imu, isg, iW, ier,
        [&](int sigma, int b0, int h, const float* num, const float* den) {
#pragma unroll
            for (int bb = 0; bb < TB; ++bb)
                wp[((size_t)sigma * NB + (b0 + bb)) * NH + h] =
                    make_float2(num[bb], den[bb]);
        });
}

__global__ __launch_bounds__(256) void ltc_epilogue_ps(
    const float* __restrict__ state,
    const float* __restrict__ vleak, const float* __restrict__ gleak,
    const float* __restrict__ cm,
    const float2* __restrict__ wp, float* __restrict__ out)
{
    const int t = blockIdx.x * 256 + threadIdx.x;
    float wnum = 0.f, wden = 0.f;
#pragma unroll
    for (int s = 0; s < NSPL; ++s) {
        const float2 v = wp[(size_t)s * NB * NH + t];
        wnum += v.x; wden += v.y;
    }
    ltc_epilogue_math(t, wnum, wden, state, vleak, gleak, cm, out);
}

// ---------------- Path B: 3-launch atomic fallback ------------------------
__global__ __launch_bounds__(256, 8) void ltc_accum(
    const float* __restrict__ inputs, const float* __restrict__ state,
    const float* __restrict__ smu, const float* __restrict__ ssg,
    const float* __restrict__ sW,  const float* __restrict__ ser,
    const float* __restrict__ imu, const float* __restrict__ isg,
    const float* __restrict__ iW,  const float* __restrict__ ier,
    float* __restrict__ wsNum, float* __restrict__ wsDen)
{
    ltc_accum_body(inputs, state, smu, ssg, sW, ser, imu, isg, iW, ier,
        [&](int /*sigma*/, int b0, int h, const float* num, const float* den) {
#pragma unroll
            for (int bb = 0; bb < TB; ++bb) {
                unsafeAtomicAdd(&wsNum[(b0 + bb) * NH + h], num[bb]);
                unsafeAtomicAdd(&wsDen[(b0 + bb) * NH + h], den[bb]);
            }
        });
}

__global__ __launch_bounds__(256) void ltc_epilogue(
    const float* __restrict__ state,
    const float* __restrict__ vleak, const float* __restrict__ gleak,
    const float* __restrict__ cm,
    const float* __restrict__ wsNum, const float* __restrict__ wsDen,
    float* __restrict__ out)
{
    const int t = blockIdx.x * 256 + threadIdx.x;
    ltc_epilogue_math(t, wsNum[t], wsDen[t], state, vleak, gleak, cm, out);
}

extern "C" void kernel_launch(void* const* d_in, const int* in_sizes, int n_in,
                              void* d_out, int out_size, void* d_ws, size_t ws_size,
                              hipStream_t stream) {
    const float* inputs = (const float*)d_in[0];
    const float* state  = (const float*)d_in[1];
    const float* smu    = (const float*)d_in[2];
    const float* ssg    = (const float*)d_in[3];
    const float* sW     = (const float*)d_in[4];
    const float* ser    = (const float*)d_in[5];
    const float* imu    = (const float*)d_in[6];
    const float* isg    = (const float*)d_in[7];
    const float* iW     = (const float*)d_in[8];
    const float* ier    = (const float*)d_in[9];
    const float* vleak  = (const float*)d_in[10];
    const float* gleak  = (const float*)d_in[11];
    const float* cm     = (const float*)d_in[12];
    float* outp = (float*)d_out;

    const size_t PS_WS = (size_t)NSPL * NB * NH * sizeof(float2);  // 32 MiB

    if (ws_size >= PS_WS) {
        float2* wp = (float2*)d_ws;
        // Path 0: single cooperative launch (harness-supported).
        void* args[] = {
            (void*)&inputs, (void*)&state,
            (void*)&smu, (void*)&ssg, (void*)&sW, (void*)&ser,
            (void*)&imu, (void*)&isg, (void*)&iW, (void*)&ier,
            (void*)&vleak, (void*)&gleak, (void*)&cm,
            (void*)&wp, (void*)&outp };
        hipError_t e = hipLaunchCooperativeKernel(
            reinterpret_cast<const void*>(ltc_fused),
            dim3(GRID), dim3(256), args, 0, stream);
        if (e == hipSuccess) return;

        // Path A: 2-launch partial-store (no memset needed).
        ltc_accum_ps<<<dim3(GRID), dim3(256), 0, stream>>>(
            inputs, state, smu, ssg, sW, ser, imu, isg, iW, ier, wp);
        ltc_epilogue_ps<<<dim3(NB * NH / 256), dim3(256), 0, stream>>>(
            state, vleak, gleak, cm, wp, outp);
        return;
    }

    // Path B: 3-launch atomics (ws re-poisoned 0xAA -> zero it ourselves).
    float* wsNum = (float*)d_ws;
    float* wsDen = wsNum + NB * NH;
    hipMemsetAsync(d_ws, 0, 2ull * NB * NH * sizeof(float), stream);
    ltc_accum<<<dim3(GRID), dim3(256), 0, stream>>>(
        inputs, state, smu, ssg, sW, ser, imu, isg, iW, ier, wsNum, wsDen);
    ltc_epilogue<<<dim3(NB * NH / 256), dim3(256), 0, stream>>>(
        state, vleak, gleak, cm, wsNum, wsDen, outp);
}